// Round 2
// baseline (925.243 us; speedup 1.0000x reference)
//
#include <hip/hip_runtime.h>
#include <math.h>

#define NB 8
#define NN 2048
#define DD 64

// ---------------- Kernel 1: h = relu(relu(x@W1+b1)@W2+b2); sq = |h|^2 ----------------
__global__ __launch_bounds__(256) void k_embed(
    const float* __restrict__ x, const float* __restrict__ W1, const float* __restrict__ b1,
    const float* __restrict__ W2, const float* __restrict__ b2,
    float* __restrict__ h, float* __restrict__ sqv)
{
    __shared__ float w2s[64 * 64];
    __shared__ float h1s[4][64];
    int tid = threadIdx.x;
    for (int q = tid; q < 4096; q += 256) w2s[q] = W2[q];
    int wave = tid >> 6, lane = tid & 63;
    int node = blockIdx.x * 4 + wave;
    const float* xr = x + node * 4;
    float x0 = xr[0], x1 = xr[1], x2 = xr[2], x3 = xr[3];
    float a = b1[lane] + x0 * W1[lane] + x1 * W1[64 + lane] + x2 * W1[128 + lane] + x3 * W1[192 + lane];
    a = fmaxf(a, 0.f);
    h1s[wave][lane] = a;
    __syncthreads();
    float acc = b2[lane];
    #pragma unroll 8
    for (int k = 0; k < 64; k++) acc += h1s[wave][k] * w2s[k * 64 + lane];
    acc = fmaxf(acc, 0.f);
    h[(long)node * 64 + lane] = acc;
    float s = acc * acc;
    #pragma unroll
    for (int m = 1; m < 64; m <<= 1) s += __shfl_xor(s, m, 64);
    if (lane == 0) sqv[node] = s;
}

// ---------------- Kernel 2: 3-NN partials, register-tiled distance GEMM ----------------
// Block = 64 i-rows x 512 j-range (1/4 of N). 256 threads: tx=tid&15 (j), ty=tid>>4 (i).
// Thread tile: 4 i (rows ty+16v) x 8 j (cols tx+16u). k in float4 chunks.
// LDS rows padded to 17 float4 (odd mod 8 -> 2-way bank aliasing only, free).
#define JS4 17
__global__ __launch_bounds__(256) void k_knn(
    const float* __restrict__ h, const float* __restrict__ sqv,
    float* __restrict__ pval, int* __restrict__ pidx)
{
    __shared__ float4 hjt[128 * JS4];   // 34816 B
    __shared__ float4 hit[64 * JS4];    // 17408 B
    __shared__ float sqj[128];
    __shared__ float sqi_s[64];

    int tid = threadIdx.x;
    int tx = tid & 15, ty = tid >> 4;
    int bx = blockIdx.x;
    int b = bx >> 7;                 // batch
    int rem = bx & 127;
    int itile = rem >> 2;            // 0..31
    int js = rem & 3;                // j-split 0..3

    long ibase = (long)b * NN + itile * 64;
    const float4* h4 = reinterpret_cast<const float4*>(h);

    // stage i-tile: 64 rows x 16 float4 (coalesced)
    #pragma unroll
    for (int q = 0; q < 4; q++) {
        int li = q * 256 + tid;
        int row = li >> 4, col = li & 15;
        hit[row * JS4 + col] = h4[(ibase + row) * 16 + col];
    }
    if (tid < 64) sqi_s[tid] = sqv[ibase + tid];

    float val[4][4]; int idx[4][4];
    #pragma unroll
    for (int v = 0; v < 4; v++)
        #pragma unroll
        for (int k = 0; k < 4; k++) { val[v][k] = 3.4e38f; idx[v][k] = 0x7fffffff; }

    long jb0 = (long)b * NN;
    for (int jt = js * 512; jt < js * 512 + 512; jt += 128) {
        __syncthreads();
        #pragma unroll
        for (int q = 0; q < 8; q++) {
            int li = q * 256 + tid;
            int row = li >> 4, col = li & 15;
            hjt[row * JS4 + col] = h4[(jb0 + jt + row) * 16 + col];
        }
        if (tid < 128) sqj[tid] = sqv[jb0 + jt + tid];
        __syncthreads();

        float acc[4][8];
        #pragma unroll
        for (int v = 0; v < 4; v++)
            #pragma unroll
            for (int u = 0; u < 8; u++) acc[v][u] = 0.f;

        for (int c = 0; c < 16; c++) {
            float4 af[4], bf[8];
            #pragma unroll
            for (int v = 0; v < 4; v++) af[v] = hit[(ty + v * 16) * JS4 + c];
            #pragma unroll
            for (int u = 0; u < 8; u++) bf[u] = hjt[(tx + u * 16) * JS4 + c];
            #pragma unroll
            for (int v = 0; v < 4; v++)
                #pragma unroll
                for (int u = 0; u < 8; u++) {
                    acc[v][u] += af[v].x * bf[u].x + af[v].y * bf[u].y
                               + af[v].z * bf[u].z + af[v].w * bf[u].w;
                }
        }

        #pragma unroll
        for (int v = 0; v < 4; v++) {
            float si = sqi_s[ty + v * 16];
            #pragma unroll
            for (int u = 0; u < 8; u++) {
                float d = si + sqj[tx + u * 16] - 2.f * acc[v][u];
                int j = jt + tx + u * 16;
                if (d < val[v][3] || (d == val[v][3] && j < idx[v][3])) {
                    #pragma unroll
                    for (int k = 0; k < 4; k++) {
                        if (d < val[v][k] || (d == val[v][k] && j < idx[v][k])) {
                            for (int m = 3; m > k; m--) { val[v][m] = val[v][m-1]; idx[v][m] = idx[v][m-1]; }
                            val[v][k] = d; idx[v][k] = j;
                            break;
                        }
                    }
                }
            }
        }
    }

    // merge 16 tx-lists of 4 per i-row (alias LDS tiles, both >= 16 KB)
    __syncthreads();
    float* mval = (float*)hjt;
    int*   midx = (int*)hit;
    #pragma unroll
    for (int v = 0; v < 4; v++)
        #pragma unroll
        for (int k = 0; k < 4; k++) {
            mval[(ty + v * 16) * 64 + tx * 4 + k] = val[v][k];
            midx[(ty + v * 16) * 64 + tx * 4 + k] = idx[v][k];
        }
    __syncthreads();
    if (tx == 0) {
        #pragma unroll
        for (int v = 0; v < 4; v++) {
            int il = ty + v * 16;
            float fv[4] = {3.4e38f, 3.4e38f, 3.4e38f, 3.4e38f};
            int   fi[4] = {0x7fffffff, 0x7fffffff, 0x7fffffff, 0x7fffffff};
            for (int t = 0; t < 64; t++) {
                float d = mval[il * 64 + t];
                int j = midx[il * 64 + t];
                if (d < fv[3] || (d == fv[3] && j < fi[3])) {
                    #pragma unroll
                    for (int k = 0; k < 4; k++) {
                        if (d < fv[k] || (d == fv[k] && j < fi[k])) {
                            for (int m = 3; m > k; m--) { fv[m] = fv[m-1]; fi[m] = fi[m-1]; }
                            fv[k] = d; fi[k] = j;
                            break;
                        }
                    }
                }
            }
            long gi = ibase + il;
            #pragma unroll
            for (int k = 0; k < 4; k++) {
                pval[gi * 16 + js * 4 + k] = fv[k];
                pidx[gi * 16 + js * 4 + k] = fi[k];
            }
        }
    }
}

// ---------------- Kernel 2b: merge 4 j-split partials -> knn[3] ----------------
__global__ __launch_bounds__(256) void k_knn_merge(
    const float* __restrict__ pval, const int* __restrict__ pidx, int* __restrict__ knn)
{
    int gi = blockIdx.x * 256 + threadIdx.x;   // 0..16383
    float fv[4] = {3.4e38f, 3.4e38f, 3.4e38f, 3.4e38f};
    int   fi[4] = {0x7fffffff, 0x7fffffff, 0x7fffffff, 0x7fffffff};
    #pragma unroll
    for (int t = 0; t < 16; t++) {
        float d = pval[(long)gi * 16 + t];
        int j = pidx[(long)gi * 16 + t];
        if (d < fv[3] || (d == fv[3] && j < fi[3])) {
            #pragma unroll
            for (int k = 0; k < 4; k++) {
                if (d < fv[k] || (d == fv[k] && j < fi[k])) {
                    for (int m = 3; m > k; m--) { fv[m] = fv[m-1]; fi[m] = fi[m-1]; }
                    fv[k] = d; fi[k] = j;
                    break;
                }
            }
        }
    }
    int* o = knn + (long)gi * 3;   // drop entry 0 (self)
    o[0] = fi[1]; o[1] = fi[2]; o[2] = fi[3];
}

// ---------------- Kernel 3: msgs -> concat -> u1 -> u2 -> heads ----------------
__global__ __launch_bounds__(256) void k_head(
    const float* __restrict__ h, const int* __restrict__ knn,
    const float* __restrict__ Wm, const float* __restrict__ bm,
    const float* __restrict__ Wu1, const float* __restrict__ bu1,
    const float* __restrict__ Wu2, const float* __restrict__ bu2,
    const float* __restrict__ Wmean, const float* __restrict__ bmean,
    const float* __restrict__ Wv, const float* __restrict__ bv,
    const float* __restrict__ log_std,
    float* __restrict__ out_mean, float* __restrict__ out_std, float* __restrict__ out_val)
{
    __shared__ __align__(16) float neigh[4][4 * 3 * 64];  // 12 KB
    __shared__ float hc[4][4][128];                        // 8 KB
    __shared__ float ub[4][4][128];                        // 8 KB

    int tid = threadIdx.x;
    int wave = tid >> 6, lane = tid & 63;
    int base = blockIdx.x * 16 + wave * 4;

    #pragma unroll
    for (int it = 0; it < 3; it++) {
        int q = lane + it * 64;            // 0..191
        int nl = q / 48, rem = q % 48;
        int nb = rem / 16, k4 = rem % 16;
        int node = base + nl;
        int bt = node >> 11;
        int j = knn[node * 3 + nb];
        const float4* src = reinterpret_cast<const float4*>(h + ((long)(bt << 11) + j) * 64);
        reinterpret_cast<float4*>(&neigh[wave][(nl * 3 + nb) * 64])[k4] = src[k4];
    }
    #pragma unroll
    for (int it = 0; it < 4; it++) {
        int q = lane + it * 64;
        int nl = q >> 6, k = q & 63;
        hc[wave][nl][k] = h[(long)(base + nl) * 64 + k];
    }
    __syncthreads();

    float accm[4][3];
    {
        float bmf = bm[lane];
        #pragma unroll
        for (int nl = 0; nl < 4; nl++)
            #pragma unroll
            for (int e = 0; e < 3; e++) accm[nl][e] = bmf;
        for (int k = 0; k < 64; k++) {
            float w = Wm[k * 64 + lane];
            #pragma unroll
            for (int nl = 0; nl < 4; nl++)
                #pragma unroll
                for (int e = 0; e < 3; e++)
                    accm[nl][e] += neigh[wave][(nl * 3 + e) * 64 + k] * w;
        }
        #pragma unroll
        for (int nl = 0; nl < 4; nl++) {
            float m = (fmaxf(accm[nl][0], 0.f) + fmaxf(accm[nl][1], 0.f) + fmaxf(accm[nl][2], 0.f)) * (1.f / 3.f);
            hc[wave][nl][64 + lane] = m;
        }
    }
    __syncthreads();

    {
        float a0[4], a1[4];
        float b0 = bu1[lane], b1v = bu1[64 + lane];
        #pragma unroll
        for (int nl = 0; nl < 4; nl++) { a0[nl] = b0; a1[nl] = b1v; }
        for (int k = 0; k < 128; k++) {
            float w0 = Wu1[k * 128 + lane];
            float w1 = Wu1[k * 128 + 64 + lane];
            #pragma unroll
            for (int nl = 0; nl < 4; nl++) {
                float v = hc[wave][nl][k];
                a0[nl] += v * w0; a1[nl] += v * w1;
            }
        }
        #pragma unroll
        for (int nl = 0; nl < 4; nl++) {
            ub[wave][nl][lane]      = fmaxf(a0[nl], 0.f);
            ub[wave][nl][64 + lane] = fmaxf(a1[nl], 0.f);
        }
    }
    __syncthreads();

    float u20[4], u21[4];
    {
        float b0 = bu2[lane], b1v = bu2[64 + lane];
        #pragma unroll
        for (int nl = 0; nl < 4; nl++) { u20[nl] = b0; u21[nl] = b1v; }
        for (int k = 0; k < 128; k++) {
            float w0 = Wu2[k * 128 + lane];
            float w1 = Wu2[k * 128 + 64 + lane];
            #pragma unroll
            for (int nl = 0; nl < 4; nl++) {
                float v = ub[wave][nl][k];
                u20[nl] += v * w0; u21[nl] += v * w1;
            }
        }
        #pragma unroll
        for (int nl = 0; nl < 4; nl++) { u20[nl] = fmaxf(u20[nl], 0.f); u21[nl] = fmaxf(u21[nl], 0.f); }
    }

    float wm0a = Wmean[lane * 2 + 0], wm0b = Wmean[(64 + lane) * 2 + 0];
    float wm1a = Wmean[lane * 2 + 1], wm1b = Wmean[(64 + lane) * 2 + 1];
    float wva  = Wv[lane],            wvb  = Wv[64 + lane];
    #pragma unroll
    for (int nl = 0; nl < 4; nl++) {
        float p0 = u20[nl] * wm0a + u21[nl] * wm0b;
        float p1 = u20[nl] * wm1a + u21[nl] * wm1b;
        float p2 = u20[nl] * wva  + u21[nl] * wvb;
        #pragma unroll
        for (int m = 1; m < 64; m <<= 1) {
            p0 += __shfl_xor(p0, m, 64);
            p1 += __shfl_xor(p1, m, 64);
            p2 += __shfl_xor(p2, m, 64);
        }
        if (lane == 0) {
            int node = base + nl;
            out_mean[node * 2 + 0] = p0 + bmean[0];
            out_mean[node * 2 + 1] = p1 + bmean[1];
            out_val[node] = p2 + bv[0];
        }
    }
    if (blockIdx.x == 0 && tid < 2) out_std[tid] = expf(log_std[tid]);
}

extern "C" void kernel_launch(void* const* d_in, const int* in_sizes, int n_in,
                              void* d_out, int out_size, void* d_ws, size_t ws_size,
                              hipStream_t stream) {
    const float* x     = (const float*)d_in[0];
    const float* W1    = (const float*)d_in[1];
    const float* b1    = (const float*)d_in[2];
    const float* W2    = (const float*)d_in[3];
    const float* b2    = (const float*)d_in[4];
    const float* Wm    = (const float*)d_in[5];
    const float* bm    = (const float*)d_in[6];
    const float* Wu1   = (const float*)d_in[7];
    const float* bu1   = (const float*)d_in[8];
    const float* Wu2   = (const float*)d_in[9];
    const float* bu2   = (const float*)d_in[10];
    const float* Wmean = (const float*)d_in[11];
    const float* bmean = (const float*)d_in[12];
    const float* Wv    = (const float*)d_in[13];
    const float* bv    = (const float*)d_in[14];
    const float* lstd  = (const float*)d_in[15];

    float* out = (float*)d_out;
    float* out_mean = out;                 // 8*2048*2 = 32768
    float* out_std  = out + 32768;         // 2
    float* out_val  = out + 32770;         // 8*2048

    float* h    = (float*)d_ws;                 // 16384*64
    float* sqv  = h + (long)16384 * 64;         // 16384
    int*   knn  = (int*)(sqv + 16384);          // 16384*3
    float* pval = (float*)(knn + 16384 * 3);    // 16384*16
    int*   pidx = (int*)(pval + 16384 * 16);    // 16384*16

    k_embed<<<4096, 256, 0, stream>>>(x, W1, b1, W2, b2, h, sqv);
    k_knn<<<1024, 256, 0, stream>>>(h, sqv, pval, pidx);
    k_knn_merge<<<64, 256, 0, stream>>>(pval, pidx, knn);
    k_head<<<1024, 256, 0, stream>>>(h, knn, Wm, bm, Wu1, bu1, Wu2, bu2,
                                     Wmean, bmean, Wv, bv, lstd,
                                     out_mean, out_std, out_val);
}

// Round 3
// 374.702 us; speedup vs baseline: 2.4693x; 2.4693x over previous
//
#include <hip/hip_runtime.h>
#include <math.h>

#define NB 8
#define NN 2048
#define DD 64

// Branch-free sorted insert of (d,j) into ascending top-4 held in float4/int4
// registers. Constant-component access only -> can never spill to scratch.
#define INS4(vv, ii, d, j) {                                      \
    bool c0 = (d < vv.x) || (d == vv.x && j < ii.x);              \
    bool c1 = (d < vv.y) || (d == vv.y && j < ii.y);              \
    bool c2 = (d < vv.z) || (d == vv.z && j < ii.z);              \
    bool c3 = (d < vv.w) || (d == vv.w && j < ii.w);              \
    vv.w = c3 ? (c2 ? vv.z : d) : vv.w; ii.w = c3 ? (c2 ? ii.z : j) : ii.w; \
    vv.z = c2 ? (c1 ? vv.y : d) : vv.z; ii.z = c2 ? (c1 ? ii.y : j) : ii.z; \
    vv.y = c1 ? (c0 ? vv.x : d) : vv.y; ii.y = c1 ? (c0 ? ii.x : j) : ii.y; \
    vv.x = c0 ? d : vv.x;               ii.x = c0 ? j : ii.x; }

// ---------------- Kernel 1: h = relu(relu(x@W1+b1)@W2+b2); sq = |h|^2 ----------------
__global__ __launch_bounds__(256) void k_embed(
    const float* __restrict__ x, const float* __restrict__ W1, const float* __restrict__ b1,
    const float* __restrict__ W2, const float* __restrict__ b2,
    float* __restrict__ h, float* __restrict__ sqv)
{
    __shared__ float w2s[64 * 64];
    __shared__ float h1s[4][64];
    int tid = threadIdx.x;
    for (int q = tid; q < 4096; q += 256) w2s[q] = W2[q];
    int wave = tid >> 6, lane = tid & 63;
    int node = blockIdx.x * 4 + wave;
    const float* xr = x + node * 4;
    float x0 = xr[0], x1 = xr[1], x2 = xr[2], x3 = xr[3];
    float a = b1[lane] + x0 * W1[lane] + x1 * W1[64 + lane] + x2 * W1[128 + lane] + x3 * W1[192 + lane];
    a = fmaxf(a, 0.f);
    h1s[wave][lane] = a;
    __syncthreads();
    float acc = b2[lane];
    #pragma unroll 8
    for (int k = 0; k < 64; k++) acc += h1s[wave][k] * w2s[k * 64 + lane];
    acc = fmaxf(acc, 0.f);
    h[(long)node * 64 + lane] = acc;
    float s = acc * acc;
    #pragma unroll
    for (int m = 1; m < 64; m <<= 1) s += __shfl_xor(s, m, 64);
    if (lane == 0) sqv[node] = s;
}

// ---------------- Kernel 2: 3-NN partials, register-tiled distance GEMM ----------------
// Block = 64 i-rows x 512 j-range (1/4 of N). 256 threads: tx=tid&15 (j), ty=tid>>4 (i).
// Thread tile: 4 i (rows ty+16v) x 8 j (cols tx+16u). k in float4 chunks.
// LDS rows padded to 17 float4.
#define JS4 17
__global__ __launch_bounds__(256) void k_knn(
    const float* __restrict__ h, const float* __restrict__ sqv,
    float* __restrict__ pval, int* __restrict__ pidx)
{
    __shared__ float4 hjt[128 * JS4];   // 34816 B
    __shared__ float4 hit[64 * JS4];    // 17408 B
    __shared__ float sqj[128];
    __shared__ float sqi_s[64];

    int tid = threadIdx.x;
    int tx = tid & 15, ty = tid >> 4;
    int bx = blockIdx.x;
    int b = bx >> 7;                 // batch
    int rem = bx & 127;
    int itile = rem >> 2;            // 0..31
    int js = rem & 3;                // j-split 0..3

    long ibase = (long)b * NN + itile * 64;
    const float4* h4 = reinterpret_cast<const float4*>(h);

    #pragma unroll
    for (int q = 0; q < 4; q++) {
        int li = q * 256 + tid;
        int row = li >> 4, col = li & 15;
        hit[row * JS4 + col] = h4[(ibase + row) * 16 + col];
    }
    if (tid < 64) sqi_s[tid] = sqv[ibase + tid];

    float4 val[4]; int4 idx[4];
    #pragma unroll
    for (int v = 0; v < 4; v++) {
        val[v] = make_float4(3.4e38f, 3.4e38f, 3.4e38f, 3.4e38f);
        idx[v] = make_int4(0x7fffffff, 0x7fffffff, 0x7fffffff, 0x7fffffff);
    }

    long jb0 = (long)b * NN;
    for (int jt = js * 512; jt < js * 512 + 512; jt += 128) {
        __syncthreads();
        #pragma unroll
        for (int q = 0; q < 8; q++) {
            int li = q * 256 + tid;
            int row = li >> 4, col = li & 15;
            hjt[row * JS4 + col] = h4[(jb0 + jt + row) * 16 + col];
        }
        if (tid < 128) sqj[tid] = sqv[jb0 + jt + tid];
        __syncthreads();

        float acc[4][8];
        #pragma unroll
        for (int v = 0; v < 4; v++)
            #pragma unroll
            for (int u = 0; u < 8; u++) acc[v][u] = 0.f;

        for (int c = 0; c < 16; c++) {
            float4 af[4], bf[8];
            #pragma unroll
            for (int v = 0; v < 4; v++) af[v] = hit[(ty + v * 16) * JS4 + c];
            #pragma unroll
            for (int u = 0; u < 8; u++) bf[u] = hjt[(tx + u * 16) * JS4 + c];
            #pragma unroll
            for (int v = 0; v < 4; v++)
                #pragma unroll
                for (int u = 0; u < 8; u++) {
                    acc[v][u] += af[v].x * bf[u].x + af[v].y * bf[u].y
                               + af[v].z * bf[u].z + af[v].w * bf[u].w;
                }
        }

        #pragma unroll
        for (int v = 0; v < 4; v++) {
            float si = sqi_s[ty + v * 16];
            #pragma unroll
            for (int u = 0; u < 8; u++) {
                float d = si + sqj[tx + u * 16] - 2.f * acc[v][u];
                int j = jt + tx + u * 16;
                INS4(val[v], idx[v], d, j);
            }
        }
    }

    // merge 16 tx-lists of 4 per i-row (alias LDS tiles, both >= 16 KB)
    __syncthreads();
    float* mval = (float*)hjt;
    int*   midx = (int*)hit;
    #pragma unroll
    for (int v = 0; v < 4; v++) {
        int row = (ty + v * 16) * 64 + tx * 4;
        mval[row + 0] = val[v].x; mval[row + 1] = val[v].y;
        mval[row + 2] = val[v].z; mval[row + 3] = val[v].w;
        midx[row + 0] = idx[v].x; midx[row + 1] = idx[v].y;
        midx[row + 2] = idx[v].z; midx[row + 3] = idx[v].w;
    }
    __syncthreads();
    if (tx == 0) {
        #pragma unroll
        for (int v = 0; v < 4; v++) {
            int il = ty + v * 16;
            float4 fv = make_float4(3.4e38f, 3.4e38f, 3.4e38f, 3.4e38f);
            int4   fi = make_int4(0x7fffffff, 0x7fffffff, 0x7fffffff, 0x7fffffff);
            for (int t = 0; t < 64; t++) {
                float d = mval[il * 64 + t];
                int j = midx[il * 64 + t];
                INS4(fv, fi, d, j);
            }
            long gi = ibase + il;
            pval[gi * 16 + js * 4 + 0] = fv.x; pidx[gi * 16 + js * 4 + 0] = fi.x;
            pval[gi * 16 + js * 4 + 1] = fv.y; pidx[gi * 16 + js * 4 + 1] = fi.y;
            pval[gi * 16 + js * 4 + 2] = fv.z; pidx[gi * 16 + js * 4 + 2] = fi.z;
            pval[gi * 16 + js * 4 + 3] = fv.w; pidx[gi * 16 + js * 4 + 3] = fi.w;
        }
    }
}

// ---------------- Kernel 2b: merge 4 j-split partials -> knn[3] ----------------
__global__ __launch_bounds__(256) void k_knn_merge(
    const float* __restrict__ pval, const int* __restrict__ pidx, int* __restrict__ knn)
{
    int gi = blockIdx.x * 256 + threadIdx.x;   // 0..16383
    float4 fv = make_float4(3.4e38f, 3.4e38f, 3.4e38f, 3.4e38f);
    int4   fi = make_int4(0x7fffffff, 0x7fffffff, 0x7fffffff, 0x7fffffff);
    #pragma unroll
    for (int t = 0; t < 16; t++) {
        float d = pval[(long)gi * 16 + t];
        int j = pidx[(long)gi * 16 + t];
        INS4(fv, fi, d, j);
    }
    int* o = knn + (long)gi * 3;   // drop entry 0 (self)
    o[0] = fi.y; o[1] = fi.z; o[2] = fi.w;
}

// ---------------- Kernel 3: msgs -> concat -> u1 -> u2 -> heads ----------------
__global__ __launch_bounds__(256) void k_head(
    const float* __restrict__ h, const int* __restrict__ knn,
    const float* __restrict__ Wm, const float* __restrict__ bm,
    const float* __restrict__ Wu1, const float* __restrict__ bu1,
    const float* __restrict__ Wu2, const float* __restrict__ bu2,
    const float* __restrict__ Wmean, const float* __restrict__ bmean,
    const float* __restrict__ Wv, const float* __restrict__ bv,
    const float* __restrict__ log_std,
    float* __restrict__ out_mean, float* __restrict__ out_std, float* __restrict__ out_val)
{
    __shared__ __align__(16) float neigh[4][4 * 3 * 64];  // 12 KB
    __shared__ float hc[4][4][128];                        // 8 KB
    __shared__ float ub[4][4][128];                        // 8 KB

    int tid = threadIdx.x;
    int wave = tid >> 6, lane = tid & 63;
    int base = blockIdx.x * 16 + wave * 4;

    #pragma unroll
    for (int it = 0; it < 3; it++) {
        int q = lane + it * 64;            // 0..191
        int nl = q / 48, rem = q % 48;
        int nb = rem / 16, k4 = rem % 16;
        int node = base + nl;
        int bt = node >> 11;
        int j = knn[node * 3 + nb];
        const float4* src = reinterpret_cast<const float4*>(h + ((long)(bt << 11) + j) * 64);
        reinterpret_cast<float4*>(&neigh[wave][(nl * 3 + nb) * 64])[k4] = src[k4];
    }
    #pragma unroll
    for (int it = 0; it < 4; it++) {
        int q = lane + it * 64;
        int nl = q >> 6, k = q & 63;
        hc[wave][nl][k] = h[(long)(base + nl) * 64 + k];
    }
    __syncthreads();

    float accm[4][3];
    {
        float bmf = bm[lane];
        #pragma unroll
        for (int nl = 0; nl < 4; nl++)
            #pragma unroll
            for (int e = 0; e < 3; e++) accm[nl][e] = bmf;
        for (int k = 0; k < 64; k++) {
            float w = Wm[k * 64 + lane];
            #pragma unroll
            for (int nl = 0; nl < 4; nl++)
                #pragma unroll
                for (int e = 0; e < 3; e++)
                    accm[nl][e] += neigh[wave][(nl * 3 + e) * 64 + k] * w;
        }
        #pragma unroll
        for (int nl = 0; nl < 4; nl++) {
            float m = (fmaxf(accm[nl][0], 0.f) + fmaxf(accm[nl][1], 0.f) + fmaxf(accm[nl][2], 0.f)) * (1.f / 3.f);
            hc[wave][nl][64 + lane] = m;
        }
    }
    __syncthreads();

    {
        float a0[4], a1[4];
        float b0 = bu1[lane], b1v = bu1[64 + lane];
        #pragma unroll
        for (int nl = 0; nl < 4; nl++) { a0[nl] = b0; a1[nl] = b1v; }
        for (int k = 0; k < 128; k++) {
            float w0 = Wu1[k * 128 + lane];
            float w1 = Wu1[k * 128 + 64 + lane];
            #pragma unroll
            for (int nl = 0; nl < 4; nl++) {
                float v = hc[wave][nl][k];
                a0[nl] += v * w0; a1[nl] += v * w1;
            }
        }
        #pragma unroll
        for (int nl = 0; nl < 4; nl++) {
            ub[wave][nl][lane]      = fmaxf(a0[nl], 0.f);
            ub[wave][nl][64 + lane] = fmaxf(a1[nl], 0.f);
        }
    }
    __syncthreads();

    float u20[4], u21[4];
    {
        float b0 = bu2[lane], b1v = bu2[64 + lane];
        #pragma unroll
        for (int nl = 0; nl < 4; nl++) { u20[nl] = b0; u21[nl] = b1v; }
        for (int k = 0; k < 128; k++) {
            float w0 = Wu2[k * 128 + lane];
            float w1 = Wu2[k * 128 + 64 + lane];
            #pragma unroll
            for (int nl = 0; nl < 4; nl++) {
                float v = ub[wave][nl][k];
                u20[nl] += v * w0; u21[nl] += v * w1;
            }
        }
        #pragma unroll
        for (int nl = 0; nl < 4; nl++) { u20[nl] = fmaxf(u20[nl], 0.f); u21[nl] = fmaxf(u21[nl], 0.f); }
    }

    float wm0a = Wmean[lane * 2 + 0], wm0b = Wmean[(64 + lane) * 2 + 0];
    float wm1a = Wmean[lane * 2 + 1], wm1b = Wmean[(64 + lane) * 2 + 1];
    float wva  = Wv[lane],            wvb  = Wv[64 + lane];
    #pragma unroll
    for (int nl = 0; nl < 4; nl++) {
        float p0 = u20[nl] * wm0a + u21[nl] * wm0b;
        float p1 = u20[nl] * wm1a + u21[nl] * wm1b;
        float p2 = u20[nl] * wva  + u21[nl] * wvb;
        #pragma unroll
        for (int m = 1; m < 64; m <<= 1) {
            p0 += __shfl_xor(p0, m, 64);
            p1 += __shfl_xor(p1, m, 64);
            p2 += __shfl_xor(p2, m, 64);
        }
        if (lane == 0) {
            int node = base + nl;
            out_mean[node * 2 + 0] = p0 + bmean[0];
            out_mean[node * 2 + 1] = p1 + bmean[1];
            out_val[node] = p2 + bv[0];
        }
    }
    if (blockIdx.x == 0 && tid < 2) out_std[tid] = expf(log_std[tid]);
}

extern "C" void kernel_launch(void* const* d_in, const int* in_sizes, int n_in,
                              void* d_out, int out_size, void* d_ws, size_t ws_size,
                              hipStream_t stream) {
    const float* x     = (const float*)d_in[0];
    const float* W1    = (const float*)d_in[1];
    const float* b1    = (const float*)d_in[2];
    const float* W2    = (const float*)d_in[3];
    const float* b2    = (const float*)d_in[4];
    const float* Wm    = (const float*)d_in[5];
    const float* bm    = (const float*)d_in[6];
    const float* Wu1   = (const float*)d_in[7];
    const float* bu1   = (const float*)d_in[8];
    const float* Wu2   = (const float*)d_in[9];
    const float* bu2   = (const float*)d_in[10];
    const float* Wmean = (const float*)d_in[11];
    const float* bmean = (const float*)d_in[12];
    const float* Wv    = (const float*)d_in[13];
    const float* bv    = (const float*)d_in[14];
    const float* lstd  = (const float*)d_in[15];

    float* out = (float*)d_out;
    float* out_mean = out;                 // 8*2048*2 = 32768
    float* out_std  = out + 32768;         // 2
    float* out_val  = out + 32770;         // 8*2048

    float* h    = (float*)d_ws;                 // 16384*64
    float* sqv  = h + (long)16384 * 64;         // 16384
    int*   knn  = (int*)(sqv + 16384);          // 16384*3
    float* pval = (float*)(knn + 16384 * 3);    // 16384*16
    int*   pidx = (int*)(pval + 16384 * 16);    // 16384*16

    k_embed<<<4096, 256, 0, stream>>>(x, W1, b1, W2, b2, h, sqv);
    k_knn<<<1024, 256, 0, stream>>>(h, sqv, pval, pidx);
    k_knn_merge<<<64, 256, 0, stream>>>(pval, pidx, knn);
    k_head<<<1024, 256, 0, stream>>>(h, knn, Wm, bm, Wu1, bu1, Wu2, bu2,
                                     Wmean, bmean, Wv, bv, lstd,
                                     out_mean, out_std, out_val);
}

// Round 4
// 277.163 us; speedup vs baseline: 3.3383x; 1.3519x over previous
//
#include <hip/hip_runtime.h>
#include <math.h>

#define NB 8
#define NN 2048

typedef short bf16x8 __attribute__((ext_vector_type(8)));
typedef float f32x4  __attribute__((ext_vector_type(4)));

__device__ __forceinline__ f32x4 mfma16(uint4 a, uint4 b, f32x4 c) {
    return __builtin_amdgcn_mfma_f32_16x16x32_bf16(
        __builtin_bit_cast(bf16x8, a), __builtin_bit_cast(bf16x8, b), c, 0, 0, 0);
}

__device__ __forceinline__ float bf2f(unsigned short u) {
    unsigned int t = ((unsigned int)u) << 16;
    return __builtin_bit_cast(float, t);
}

// Branch-free sorted insert of (d,j) into ascending top-4 in float4/int4 regs.
#define INS4(vv, ii, d, j) {                                      \
    bool c0 = (d < vv.x) || (d == vv.x && j < ii.x);              \
    bool c1 = (d < vv.y) || (d == vv.y && j < ii.y);              \
    bool c2 = (d < vv.z) || (d == vv.z && j < ii.z);              \
    bool c3 = (d < vv.w) || (d == vv.w && j < ii.w);              \
    vv.w = c3 ? (c2 ? vv.z : d) : vv.w; ii.w = c3 ? (c2 ? ii.z : j) : ii.w; \
    vv.z = c2 ? (c1 ? vv.y : d) : vv.z; ii.z = c2 ? (c1 ? ii.y : j) : ii.z; \
    vv.y = c1 ? (c0 ? vv.x : d) : vv.y; ii.y = c1 ? (c0 ? ii.x : j) : ii.y; \
    vv.x = c0 ? d : vv.x;               ii.x = c0 ? j : ii.x; }

// ---------------- Kernel 1: embed MLP; emit exact 3-way bf16 split of h + sq ----------------
// Hs layout: [node][split(3)][64] ushort. 16 nodes/block (4 per wave).
__global__ __launch_bounds__(256) void k_embed(
    const float* __restrict__ x, const float* __restrict__ W1, const float* __restrict__ b1,
    const float* __restrict__ W2, const float* __restrict__ b2,
    unsigned short* __restrict__ Hs, float* __restrict__ sqv)
{
    __shared__ float w2s[4096];
    __shared__ float h1s[4][4][64];
    int tid = threadIdx.x;
    for (int q = tid; q < 4096; q += 256) w2s[q] = W2[q];
    int wave = tid >> 6, lane = tid & 63;
    int nbase = blockIdx.x * 16 + wave * 4;
    float w10 = W1[lane], w11 = W1[64 + lane], w12 = W1[128 + lane], w13 = W1[192 + lane];
    float b1l = b1[lane];
    #pragma unroll
    for (int v = 0; v < 4; v++) {
        float4 xv = reinterpret_cast<const float4*>(x)[nbase + v];
        h1s[wave][v][lane] = fmaxf(b1l + xv.x * w10 + xv.y * w11 + xv.z * w12 + xv.w * w13, 0.f);
    }
    __syncthreads();
    float b2l = b2[lane];
    float a0 = b2l, a1 = b2l, a2 = b2l, a3 = b2l;
    for (int k = 0; k < 64; k++) {
        float w = w2s[k * 64 + lane];
        a0 += h1s[wave][0][k] * w; a1 += h1s[wave][1][k] * w;
        a2 += h1s[wave][2][k] * w; a3 += h1s[wave][3][k] * w;
    }
    float hv0 = fmaxf(a0, 0.f), hv1 = fmaxf(a1, 0.f), hv2 = fmaxf(a2, 0.f), hv3 = fmaxf(a3, 0.f);
    float hvs[4] = {hv0, hv1, hv2, hv3};
    #pragma unroll
    for (int v = 0; v < 4; v++) {
        float hval = hvs[v];
        long node = nbase + v;
        // exact 3-way truncation split: h = f0 + f1 + f2 (24 = 8+8+8 bits)
        unsigned int u0 = __builtin_bit_cast(unsigned int, hval);
        unsigned short s0 = (unsigned short)(u0 >> 16);
        float f0 = __builtin_bit_cast(float, u0 & 0xFFFF0000u);
        float r1 = hval - f0;
        unsigned int u1 = __builtin_bit_cast(unsigned int, r1);
        unsigned short s1 = (unsigned short)(u1 >> 16);
        float f1 = __builtin_bit_cast(float, u1 & 0xFFFF0000u);
        float r2 = r1 - f1;
        unsigned short s2 = (unsigned short)(__builtin_bit_cast(unsigned int, r2) >> 16);
        unsigned short* rp = Hs + node * 192;
        rp[lane] = s0; rp[64 + lane] = s1; rp[128 + lane] = s2;
        float s = hval * hval;
        #pragma unroll
        for (int m = 1; m < 64; m <<= 1) s += __shfl_xor(s, m, 64);
        if (lane == 0) sqv[node] = s;
    }
}

// ---------------- Kernel 2: 3-NN partials via MFMA (3-split bf16 gram) ----------------
// One wave = one 16-row i-group x one j-split (512 j, 32 steps of 16 cols).
// A-frag: lane holds A[m=lane&15][k=(lane>>4)*8+e]; B-frag same pattern over j-rows.
// C/D: col=lane&15, row=(lane>>4)*4+reg.
__global__ __launch_bounds__(256) void k_knn(
    const unsigned short* __restrict__ Hs, const float* __restrict__ sqv,
    float* __restrict__ pval, int* __restrict__ pidx)
{
    __shared__ float smv[4][1056];
    __shared__ int   smi[4][1056];

    int tid = threadIdx.x;
    int wave = tid >> 6, lane = tid & 63;
    int l15 = lane & 15, quad = lane >> 4;

    int job = blockIdx.x * 4 + wave;     // 0..4095
    int js  = job & 3;
    int g16 = job >> 2;                  // 0..1023
    int b   = g16 >> 7;                  // 0..7
    int grp = g16 & 127;
    int ibase = grp * 16;
    long nodeb = (long)b * NN;

    // A frags: 3 splits x 2 k-halves, loaded once
    uint4 A[3][2];
    {
        const unsigned short* ap = Hs + (nodeb + ibase + l15) * 192;
        #pragma unroll
        for (int s = 0; s < 3; s++)
            #pragma unroll
            for (int hf = 0; hf < 2; hf++)
                A[s][hf] = *reinterpret_cast<const uint4*>(ap + s * 64 + hf * 32 + quad * 8);
    }
    float si[4];
    #pragma unroll
    for (int r = 0; r < 4; r++) si[r] = sqv[nodeb + ibase + quad * 4 + r];

    float4 val[4]; int4 idx[4];
    #pragma unroll
    for (int r = 0; r < 4; r++) {
        val[r] = make_float4(3.4e38f, 3.4e38f, 3.4e38f, 3.4e38f);
        idx[r] = make_int4(0x7fffffff, 0x7fffffff, 0x7fffffff, 0x7fffffff);
    }

    const float* sqb = sqv + nodeb;
    for (int jt = js * 512; jt < js * 512 + 512; jt += 16) {
        uint4 B[3][2];
        const unsigned short* bp = Hs + (nodeb + jt + l15) * 192;
        #pragma unroll
        for (int s = 0; s < 3; s++)
            #pragma unroll
            for (int hf = 0; hf < 2; hf++)
                B[s][hf] = *reinterpret_cast<const uint4*>(bp + s * 64 + hf * 32 + quad * 8);
        float sj = sqb[jt + l15];

        f32x4 acc = {0.f, 0.f, 0.f, 0.f};
        #pragma unroll
        for (int hf = 0; hf < 2; hf++) {
            acc = mfma16(A[0][hf], B[0][hf], acc);   // hi*hi  (1)
            acc = mfma16(A[0][hf], B[1][hf], acc);   // hi*mid (2^-9)
            acc = mfma16(A[1][hf], B[0][hf], acc);   // mid*hi (2^-9)
            acc = mfma16(A[1][hf], B[1][hf], acc);   // mid*mid(2^-18)
            acc = mfma16(A[0][hf], B[2][hf], acc);   // hi*lo  (2^-18)
            acc = mfma16(A[2][hf], B[0][hf], acc);   // lo*hi  (2^-18)
        }

        int j = jt + l15;
        #pragma unroll
        for (int r = 0; r < 4; r++) {
            float d = si[r] + sj - 2.f * acc[r];
            INS4(val[r], idx[r], d, j);
        }
    }

    // stash per-lane lists: row-major with stride 65 (65 % 32 == 1 -> conflict-lite)
    float* mv = smv[wave]; int* mi = smi[wave];
    #pragma unroll
    for (int r = 0; r < 4; r++) {
        int base = (quad * 4 + r) * 65 + l15 * 4;
        mv[base + 0] = val[r].x; mv[base + 1] = val[r].y;
        mv[base + 2] = val[r].z; mv[base + 3] = val[r].w;
        mi[base + 0] = idx[r].x; mi[base + 1] = idx[r].y;
        mi[base + 2] = idx[r].z; mi[base + 3] = idx[r].w;
    }
    __syncthreads();

    // lane handles row (lane&15), chunk quad: merge 4 lists of 4
    float4 fv = make_float4(3.4e38f, 3.4e38f, 3.4e38f, 3.4e38f);
    int4   fi = make_int4(0x7fffffff, 0x7fffffff, 0x7fffffff, 0x7fffffff);
    #pragma unroll
    for (int tt = 0; tt < 4; tt++) {
        int base = l15 * 65 + (quad * 4 + tt) * 4;
        #pragma unroll
        for (int k = 0; k < 4; k++) {
            float d = mv[base + k];
            int j = mi[base + k];
            INS4(fv, fi, d, j);
        }
    }
    // butterfly across quads (xor 16, 32)
    #pragma unroll
    for (int m = 16; m <= 32; m <<= 1) {
        float ov0 = __shfl_xor(fv.x, m, 64), ov1 = __shfl_xor(fv.y, m, 64);
        float ov2 = __shfl_xor(fv.z, m, 64), ov3 = __shfl_xor(fv.w, m, 64);
        int   oi0 = __shfl_xor(fi.x, m, 64), oi1 = __shfl_xor(fi.y, m, 64);
        int   oi2 = __shfl_xor(fi.z, m, 64), oi3 = __shfl_xor(fi.w, m, 64);
        INS4(fv, fi, ov0, oi0); INS4(fv, fi, ov1, oi1);
        INS4(fv, fi, ov2, oi2); INS4(fv, fi, ov3, oi3);
    }
    if (quad == 0) {
        long gi = nodeb + ibase + l15;
        pval[gi * 16 + js * 4 + 0] = fv.x; pidx[gi * 16 + js * 4 + 0] = fi.x;
        pval[gi * 16 + js * 4 + 1] = fv.y; pidx[gi * 16 + js * 4 + 1] = fi.y;
        pval[gi * 16 + js * 4 + 2] = fv.z; pidx[gi * 16 + js * 4 + 2] = fi.z;
        pval[gi * 16 + js * 4 + 3] = fv.w; pidx[gi * 16 + js * 4 + 3] = fi.w;
    }
}

// ---------------- Kernel 2b: merge 4 j-split partials -> knn[3] ----------------
__global__ __launch_bounds__(256) void k_knn_merge(
    const float* __restrict__ pval, const int* __restrict__ pidx, int* __restrict__ knn)
{
    int gi = blockIdx.x * 256 + threadIdx.x;
    float4 fv = make_float4(3.4e38f, 3.4e38f, 3.4e38f, 3.4e38f);
    int4   fi = make_int4(0x7fffffff, 0x7fffffff, 0x7fffffff, 0x7fffffff);
    #pragma unroll
    for (int t = 0; t < 16; t++) {
        float d = pval[(long)gi * 16 + t];
        int j = pidx[(long)gi * 16 + t];
        INS4(fv, fi, d, j);
    }
    int* o = knn + (long)gi * 3;   // drop entry 0 (self)
    o[0] = fi.y; o[1] = fi.z; o[2] = fi.w;
}

// ---------------- Kernel 3: msgs -> concat -> u1 -> u2 -> heads ----------------
// 32 nodes/block, 8 per wave; h reconstructed exactly from the 3-way split.
__global__ __launch_bounds__(256) void k_head(
    const unsigned short* __restrict__ Hs, const int* __restrict__ knn,
    const float* __restrict__ Wm, const float* __restrict__ bm,
    const float* __restrict__ Wu1, const float* __restrict__ bu1,
    const float* __restrict__ Wu2, const float* __restrict__ bu2,
    const float* __restrict__ Wmean, const float* __restrict__ bmean,
    const float* __restrict__ Wv, const float* __restrict__ bv,
    const float* __restrict__ log_std,
    float* __restrict__ out_mean, float* __restrict__ out_std, float* __restrict__ out_val)
{
    __shared__ float neigh[4][8 * 3 * 64];   // 24 KB
    __shared__ float hc[4][8][128];          // 16 KB
    __shared__ float ub[4][8][128];          // 16 KB

    int tid = threadIdx.x;
    int wave = tid >> 6, lane = tid & 63;
    int base = blockIdx.x * 32 + wave * 8;

    // gather neighbors: 8 nodes x 3 nb x 16 float4-chunks = 384, 6 per lane
    #pragma unroll
    for (int it = 0; it < 6; it++) {
        int q = lane + it * 64;
        int nl = q / 48, rem = q % 48;
        int nb = rem >> 4, k4 = rem & 15;
        int node = base + nl;
        int bt = node >> 11;
        int j = knn[node * 3 + nb];
        const unsigned short* rp = Hs + ((long)(bt << 11) + j) * 192;
        ushort4 u0 = reinterpret_cast<const ushort4*>(rp)[k4];
        ushort4 u1 = reinterpret_cast<const ushort4*>(rp + 64)[k4];
        ushort4 u2 = reinterpret_cast<const ushort4*>(rp + 128)[k4];
        float4 hv;
        hv.x = bf2f(u0.x) + bf2f(u1.x) + bf2f(u2.x);
        hv.y = bf2f(u0.y) + bf2f(u1.y) + bf2f(u2.y);
        hv.z = bf2f(u0.z) + bf2f(u1.z) + bf2f(u2.z);
        hv.w = bf2f(u0.w) + bf2f(u1.w) + bf2f(u2.w);
        reinterpret_cast<float4*>(&neigh[wave][(nl * 3 + nb) * 64])[k4] = hv;
    }
    // own h: 8 nodes x 16 chunks = 128, 2 per lane
    #pragma unroll
    for (int it = 0; it < 2; it++) {
        int q = lane + it * 64;
        int nl = q >> 4, k4 = q & 15;
        const unsigned short* rp = Hs + (long)(base + nl) * 192;
        ushort4 u0 = reinterpret_cast<const ushort4*>(rp)[k4];
        ushort4 u1 = reinterpret_cast<const ushort4*>(rp + 64)[k4];
        ushort4 u2 = reinterpret_cast<const ushort4*>(rp + 128)[k4];
        float4 hv;
        hv.x = bf2f(u0.x) + bf2f(u1.x) + bf2f(u2.x);
        hv.y = bf2f(u0.y) + bf2f(u1.y) + bf2f(u2.y);
        hv.z = bf2f(u0.z) + bf2f(u1.z) + bf2f(u2.z);
        hv.w = bf2f(u0.w) + bf2f(u1.w) + bf2f(u2.w);
        reinterpret_cast<float4*>(&hc[wave][nl][0])[k4] = hv;
    }
    __syncthreads();

    // msgs
    {
        float am[8][3];
        float bmf = bm[lane];
        #pragma unroll
        for (int nl = 0; nl < 8; nl++)
            #pragma unroll
            for (int e = 0; e < 3; e++) am[nl][e] = bmf;
        for (int k = 0; k < 64; k++) {
            float w = Wm[k * 64 + lane];
            #pragma unroll
            for (int nl = 0; nl < 8; nl++)
                #pragma unroll
                for (int e = 0; e < 3; e++)
                    am[nl][e] += neigh[wave][(nl * 3 + e) * 64 + k] * w;
        }
        #pragma unroll
        for (int nl = 0; nl < 8; nl++) {
            float m = (fmaxf(am[nl][0], 0.f) + fmaxf(am[nl][1], 0.f) + fmaxf(am[nl][2], 0.f)) * (1.f / 3.f);
            hc[wave][nl][64 + lane] = m;
        }
    }
    __syncthreads();

    // u1
    {
        float a0[8], a1[8];
        float b0 = bu1[lane], b1v = bu1[64 + lane];
        #pragma unroll
        for (int nl = 0; nl < 8; nl++) { a0[nl] = b0; a1[nl] = b1v; }
        for (int k = 0; k < 128; k++) {
            float w0 = Wu1[k * 128 + lane];
            float w1 = Wu1[k * 128 + 64 + lane];
            #pragma unroll
            for (int nl = 0; nl < 8; nl++) {
                float v = hc[wave][nl][k];
                a0[nl] += v * w0; a1[nl] += v * w1;
            }
        }
        #pragma unroll
        for (int nl = 0; nl < 8; nl++) {
            ub[wave][nl][lane]      = fmaxf(a0[nl], 0.f);
            ub[wave][nl][64 + lane] = fmaxf(a1[nl], 0.f);
        }
    }
    __syncthreads();

    // u2 in regs
    float u20[8], u21[8];
    {
        float b0 = bu2[lane], b1v = bu2[64 + lane];
        #pragma unroll
        for (int nl = 0; nl < 8; nl++) { u20[nl] = b0; u21[nl] = b1v; }
        for (int k = 0; k < 128; k++) {
            float w0 = Wu2[k * 128 + lane];
            float w1 = Wu2[k * 128 + 64 + lane];
            #pragma unroll
            for (int nl = 0; nl < 8; nl++) {
                float v = ub[wave][nl][k];
                u20[nl] += v * w0; u21[nl] += v * w1;
            }
        }
        #pragma unroll
        for (int nl = 0; nl < 8; nl++) { u20[nl] = fmaxf(u20[nl], 0.f); u21[nl] = fmaxf(u21[nl], 0.f); }
    }

    float wm0a = Wmean[lane * 2 + 0], wm0b = Wmean[(64 + lane) * 2 + 0];
    float wm1a = Wmean[lane * 2 + 1], wm1b = Wmean[(64 + lane) * 2 + 1];
    float wva  = Wv[lane],            wvb  = Wv[64 + lane];
    #pragma unroll
    for (int nl = 0; nl < 8; nl++) {
        float p0 = u20[nl] * wm0a + u21[nl] * wm0b;
        float p1 = u20[nl] * wm1a + u21[nl] * wm1b;
        float p2 = u20[nl] * wva  + u21[nl] * wvb;
        #pragma unroll
        for (int m = 1; m < 64; m <<= 1) {
            p0 += __shfl_xor(p0, m, 64);
            p1 += __shfl_xor(p1, m, 64);
            p2 += __shfl_xor(p2, m, 64);
        }
        if (lane == 0) {
            int node = base + nl;
            out_mean[node * 2 + 0] = p0 + bmean[0];
            out_mean[node * 2 + 1] = p1 + bmean[1];
            out_val[node] = p2 + bv[0];
        }
    }
    if (blockIdx.x == 0 && tid < 2) out_std[tid] = expf(log_std[tid]);
}

extern "C" void kernel_launch(void* const* d_in, const int* in_sizes, int n_in,
                              void* d_out, int out_size, void* d_ws, size_t ws_size,
                              hipStream_t stream) {
    const float* x     = (const float*)d_in[0];
    const float* W1    = (const float*)d_in[1];
    const float* b1    = (const float*)d_in[2];
    const float* W2    = (const float*)d_in[3];
    const float* b2    = (const float*)d_in[4];
    const float* Wm    = (const float*)d_in[5];
    const float* bm    = (const float*)d_in[6];
    const float* Wu1   = (const float*)d_in[7];
    const float* bu1   = (const float*)d_in[8];
    const float* Wu2   = (const float*)d_in[9];
    const float* bu2   = (const float*)d_in[10];
    const float* Wmean = (const float*)d_in[11];
    const float* bmean = (const float*)d_in[12];
    const float* Wv    = (const float*)d_in[13];
    const float* bv    = (const float*)d_in[14];
    const float* lstd  = (const float*)d_in[15];

    float* out = (float*)d_out;
    float* out_mean = out;                 // 8*2048*2
    float* out_std  = out + 32768;         // 2
    float* out_val  = out + 32770;         // 8*2048

    unsigned short* Hs = (unsigned short*)d_ws;            // 16384*192 ushort = 6 MB
    float* sqv  = (float*)(Hs + (long)16384 * 192);        // 16384
    int*   knn  = (int*)(sqv + 16384);                     // 16384*3
    float* pval = (float*)(knn + 16384 * 3);               // 16384*16
    int*   pidx = (int*)(pval + (long)16384 * 16);         // 16384*16

    k_embed<<<1024, 256, 0, stream>>>(x, W1, b1, W2, b2, Hs, sqv);
    k_knn<<<1024, 256, 0, stream>>>(Hs, sqv, pval, pidx);
    k_knn_merge<<<64, 256, 0, stream>>>(pval, pidx, knn);
    k_head<<<512, 256, 0, stream>>>(Hs, knn, Wm, bm, Wu1, bu1, Wu2, bu2,
                                    Wmean, bmean, Wv, bv, lstd,
                                    out_mean, out_std, out_val);
}

// Round 5
// 254.883 us; speedup vs baseline: 3.6301x; 1.0874x over previous
//
#include <hip/hip_runtime.h>
#include <math.h>

#define NB 8
#define NN 2048

typedef short bf16x8 __attribute__((ext_vector_type(8)));
typedef float f32x4  __attribute__((ext_vector_type(4)));

__device__ __forceinline__ f32x4 mfma16(uint4 a, uint4 b, f32x4 c) {
    return __builtin_amdgcn_mfma_f32_16x16x32_bf16(
        __builtin_bit_cast(bf16x8, a), __builtin_bit_cast(bf16x8, b), c, 0, 0, 0);
}

__device__ __forceinline__ float bf2f(unsigned short u) {
    unsigned int t = ((unsigned int)u) << 16;
    return __builtin_bit_cast(float, t);
}

// Full sorted insert with jax tie-break (d==, smaller j wins) — for merges.
#define INS4(vv, ii, d, j) {                                      \
    bool c0 = (d < vv.x) || (d == vv.x && j < ii.x);              \
    bool c1 = (d < vv.y) || (d == vv.y && j < ii.y);              \
    bool c2 = (d < vv.z) || (d == vv.z && j < ii.z);              \
    bool c3 = (d < vv.w) || (d == vv.w && j < ii.w);              \
    vv.w = c3 ? (c2 ? vv.z : d) : vv.w; ii.w = c3 ? (c2 ? ii.z : j) : ii.w; \
    vv.z = c2 ? (c1 ? vv.y : d) : vv.z; ii.z = c2 ? (c1 ? ii.y : j) : ii.z; \
    vv.y = c1 ? (c0 ? vv.x : d) : vv.y; ii.y = c1 ? (c0 ? ii.x : j) : ii.y; \
    vv.x = c0 ? d : vv.x;               ii.x = c0 ? j : ii.x; }

// Strict-< insert: valid when candidates arrive in ascending j within the lane
// (equal d -> incumbent/earlier j kept, which IS the jax tie-break).
#define INS4S(vv, ii, d, j) {                                     \
    bool c0 = (d < vv.x); bool c1 = (d < vv.y);                   \
    bool c2 = (d < vv.z); bool c3 = (d < vv.w);                   \
    vv.w = c3 ? (c2 ? vv.z : d) : vv.w; ii.w = c3 ? (c2 ? ii.z : j) : ii.w; \
    vv.z = c2 ? (c1 ? vv.y : d) : vv.z; ii.z = c2 ? (c1 ? ii.y : j) : ii.z; \
    vv.y = c1 ? (c0 ? vv.x : d) : vv.y; ii.y = c1 ? (c0 ? ii.x : j) : ii.y; \
    vv.x = c0 ? d : vv.x;               ii.x = c0 ? j : ii.x; }

// ---------------- Kernel 1: embed MLP; emit exact 3-way bf16 split of h + sq ----------------
__global__ __launch_bounds__(256) void k_embed(
    const float* __restrict__ x, const float* __restrict__ W1, const float* __restrict__ b1,
    const float* __restrict__ W2, const float* __restrict__ b2,
    unsigned short* __restrict__ Hs, float* __restrict__ sqv)
{
    __shared__ float w2s[4096];
    __shared__ float h1s[4][4][64];
    int tid = threadIdx.x;
    for (int q = tid; q < 4096; q += 256) w2s[q] = W2[q];
    int wave = tid >> 6, lane = tid & 63;
    int nbase = blockIdx.x * 16 + wave * 4;
    float w10 = W1[lane], w11 = W1[64 + lane], w12 = W1[128 + lane], w13 = W1[192 + lane];
    float b1l = b1[lane];
    #pragma unroll
    for (int v = 0; v < 4; v++) {
        float4 xv = reinterpret_cast<const float4*>(x)[nbase + v];
        h1s[wave][v][lane] = fmaxf(b1l + xv.x * w10 + xv.y * w11 + xv.z * w12 + xv.w * w13, 0.f);
    }
    __syncthreads();
    float b2l = b2[lane];
    float a0 = b2l, a1 = b2l, a2 = b2l, a3 = b2l;
    for (int k = 0; k < 64; k++) {
        float w = w2s[k * 64 + lane];
        a0 += h1s[wave][0][k] * w; a1 += h1s[wave][1][k] * w;
        a2 += h1s[wave][2][k] * w; a3 += h1s[wave][3][k] * w;
    }
    float hvs[4] = {fmaxf(a0, 0.f), fmaxf(a1, 0.f), fmaxf(a2, 0.f), fmaxf(a3, 0.f)};
    #pragma unroll
    for (int v = 0; v < 4; v++) {
        float hval = hvs[v];
        long node = nbase + v;
        unsigned int u0 = __builtin_bit_cast(unsigned int, hval);
        unsigned short s0 = (unsigned short)(u0 >> 16);
        float f0 = __builtin_bit_cast(float, u0 & 0xFFFF0000u);
        float r1 = hval - f0;
        unsigned int u1 = __builtin_bit_cast(unsigned int, r1);
        unsigned short s1 = (unsigned short)(u1 >> 16);
        float f1 = __builtin_bit_cast(float, u1 & 0xFFFF0000u);
        float r2 = r1 - f1;
        unsigned short s2 = (unsigned short)(__builtin_bit_cast(unsigned int, r2) >> 16);
        unsigned short* rp = Hs + node * 192;
        rp[lane] = s0; rp[64 + lane] = s1; rp[128 + lane] = s2;
        float s = hval * hval;
        #pragma unroll
        for (int m = 1; m < 64; m <<= 1) s += __shfl_xor(s, m, 64);
        if (lane == 0) sqv[node] = s;
    }
}

// ---------------- Kernel 2: 3-NN partials via MFMA, register double-buffered B ----------------
__global__ __launch_bounds__(256) void k_knn(
    const unsigned short* __restrict__ Hs, const float* __restrict__ sqv,
    float* __restrict__ pval, int* __restrict__ pidx)
{
    __shared__ float smv[4][1056];
    __shared__ int   smi[4][1056];

    int tid = threadIdx.x;
    int wave = tid >> 6, lane = tid & 63;
    int l15 = lane & 15, quad = lane >> 4;

    int job = blockIdx.x * 4 + wave;     // 0..4095
    int js  = job & 3;
    int g16 = job >> 2;
    int b   = g16 >> 7;
    int grp = g16 & 127;
    int ibase = grp * 16;
    long nodeb = (long)b * NN;

    const unsigned short* Hsb = Hs + nodeb * 192;
    const float* sqb = sqv + nodeb;

    uint4 A[3][2];
    {
        const unsigned short* ap = Hsb + (long)(ibase + l15) * 192;
        #pragma unroll
        for (int s = 0; s < 3; s++)
            #pragma unroll
            for (int hf = 0; hf < 2; hf++)
                A[s][hf] = *reinterpret_cast<const uint4*>(ap + s * 64 + hf * 32 + quad * 8);
    }
    float si[4];
    #pragma unroll
    for (int r = 0; r < 4; r++) si[r] = sqv[nodeb + ibase + quad * 4 + r];

    float4 val[4]; int4 idx[4];
    #pragma unroll
    for (int r = 0; r < 4; r++) {
        val[r] = make_float4(3.4e38f, 3.4e38f, 3.4e38f, 3.4e38f);
        idx[r] = make_int4(0x7fffffff, 0x7fffffff, 0x7fffffff, 0x7fffffff);
    }

    int jbase = js * 512;

#define LOADB(B, SJ, J) {                                                     \
    const unsigned short* bp = Hsb + (long)((J) + l15) * 192;                 \
    _Pragma("unroll")                                                         \
    for (int s = 0; s < 3; s++)                                               \
        _Pragma("unroll")                                                     \
        for (int hf = 0; hf < 2; hf++)                                        \
            B[s][hf] = *reinterpret_cast<const uint4*>(bp + s * 64 + hf * 32 + quad * 8); \
    SJ = sqb[(J) + l15]; }

#define COMPUTE(B, SJ, J) {                                                   \
    f32x4 acc = {0.f, 0.f, 0.f, 0.f};                                         \
    _Pragma("unroll")                                                         \
    for (int hf = 0; hf < 2; hf++) {                                          \
        acc = mfma16(A[0][hf], B[0][hf], acc);                                \
        acc = mfma16(A[0][hf], B[1][hf], acc);                                \
        acc = mfma16(A[1][hf], B[0][hf], acc);                                \
        acc = mfma16(A[1][hf], B[1][hf], acc);                                \
        acc = mfma16(A[0][hf], B[2][hf], acc);                                \
        acc = mfma16(A[2][hf], B[0][hf], acc);                                \
    }                                                                         \
    int j = (J) + l15;                                                        \
    _Pragma("unroll")                                                         \
    for (int r = 0; r < 4; r++) {                                             \
        float d = si[r] + SJ - 2.f * acc[r];                                  \
        INS4S(val[r], idx[r], d, j);                                          \
    } }

    uint4 B0[3][2], B1[3][2];
    float sj0, sj1;
    LOADB(B0, sj0, jbase);

    #pragma unroll 1
    for (int t = 0; t < 16; t++) {
        int jA = jbase + t * 32;
        int jB = jA + 16;
        int jC = jbase + ((t * 32 + 32) & 511);   // wraps on last iter (dummy prefetch)
        LOADB(B1, sj1, jB);
        COMPUTE(B0, sj0, jA);
        LOADB(B0, sj0, jC);
        COMPUTE(B1, sj1, jB);
    }

    // stash per-lane lists (stride 65 to avoid pow2 conflicts)
    float* mv = smv[wave]; int* mi = smi[wave];
    #pragma unroll
    for (int r = 0; r < 4; r++) {
        int base = (quad * 4 + r) * 65 + l15 * 4;
        mv[base + 0] = val[r].x; mv[base + 1] = val[r].y;
        mv[base + 2] = val[r].z; mv[base + 3] = val[r].w;
        mi[base + 0] = idx[r].x; mi[base + 1] = idx[r].y;
        mi[base + 2] = idx[r].z; mi[base + 3] = idx[r].w;
    }
    __syncthreads();

    float4 fv = make_float4(3.4e38f, 3.4e38f, 3.4e38f, 3.4e38f);
    int4   fi = make_int4(0x7fffffff, 0x7fffffff, 0x7fffffff, 0x7fffffff);
    #pragma unroll
    for (int tt = 0; tt < 4; tt++) {
        int base = l15 * 65 + (quad * 4 + tt) * 4;
        #pragma unroll
        for (int k = 0; k < 4; k++) {
            float d = mv[base + k];
            int j = mi[base + k];
            INS4(fv, fi, d, j);
        }
    }
    #pragma unroll
    for (int m = 16; m <= 32; m <<= 1) {
        float ov0 = __shfl_xor(fv.x, m, 64), ov1 = __shfl_xor(fv.y, m, 64);
        float ov2 = __shfl_xor(fv.z, m, 64), ov3 = __shfl_xor(fv.w, m, 64);
        int   oi0 = __shfl_xor(fi.x, m, 64), oi1 = __shfl_xor(fi.y, m, 64);
        int   oi2 = __shfl_xor(fi.z, m, 64), oi3 = __shfl_xor(fi.w, m, 64);
        INS4(fv, fi, ov0, oi0); INS4(fv, fi, ov1, oi1);
        INS4(fv, fi, ov2, oi2); INS4(fv, fi, ov3, oi3);
    }
    if (quad == 0) {
        long gi = nodeb + ibase + l15;
        pval[gi * 16 + js * 4 + 0] = fv.x; pidx[gi * 16 + js * 4 + 0] = fi.x;
        pval[gi * 16 + js * 4 + 1] = fv.y; pidx[gi * 16 + js * 4 + 1] = fi.y;
        pval[gi * 16 + js * 4 + 2] = fv.z; pidx[gi * 16 + js * 4 + 2] = fi.z;
        pval[gi * 16 + js * 4 + 3] = fv.w; pidx[gi * 16 + js * 4 + 3] = fi.w;
    }
}

// ---------------- Kernel 2b: merge 4 j-split partials -> knn[3] ----------------
__global__ __launch_bounds__(256) void k_knn_merge(
    const float* __restrict__ pval, const int* __restrict__ pidx, int* __restrict__ knn)
{
    int gi = blockIdx.x * 256 + threadIdx.x;
    float4 fv = make_float4(3.4e38f, 3.4e38f, 3.4e38f, 3.4e38f);
    int4   fi = make_int4(0x7fffffff, 0x7fffffff, 0x7fffffff, 0x7fffffff);
    #pragma unroll
    for (int t = 0; t < 16; t++) {
        float d = pval[(long)gi * 16 + t];
        int j = pidx[(long)gi * 16 + t];
        INS4(fv, fi, d, j);
    }
    int* o = knn + (long)gi * 3;
    o[0] = fi.y; o[1] = fi.z; o[2] = fi.w;
}

// ---------------- Kernel 3: msgs -> concat -> u1 -> u2 -> heads ----------------
__global__ __launch_bounds__(256) void k_head(
    const unsigned short* __restrict__ Hs, const int* __restrict__ knn,
    const float* __restrict__ Wm, const float* __restrict__ bm,
    const float* __restrict__ Wu1, const float* __restrict__ bu1,
    const float* __restrict__ Wu2, const float* __restrict__ bu2,
    const float* __restrict__ Wmean, const float* __restrict__ bmean,
    const float* __restrict__ Wv, const float* __restrict__ bv,
    const float* __restrict__ log_std,
    float* __restrict__ out_mean, float* __restrict__ out_std, float* __restrict__ out_val)
{
    __shared__ float neigh[4][8 * 3 * 64];
    __shared__ float hc[4][8][128];
    __shared__ float ub[4][8][128];

    int tid = threadIdx.x;
    int wave = tid >> 6, lane = tid & 63;
    int base = blockIdx.x * 32 + wave * 8;

    #pragma unroll
    for (int it = 0; it < 6; it++) {
        int q = lane + it * 64;
        int nl = q / 48, rem = q % 48;
        int nb = rem >> 4, k4 = rem & 15;
        int node = base + nl;
        int bt = node >> 11;
        int j = knn[node * 3 + nb];
        const unsigned short* rp = Hs + ((long)(bt << 11) + j) * 192;
        ushort4 u0 = reinterpret_cast<const ushort4*>(rp)[k4];
        ushort4 u1 = reinterpret_cast<const ushort4*>(rp + 64)[k4];
        ushort4 u2 = reinterpret_cast<const ushort4*>(rp + 128)[k4];
        float4 hv;
        hv.x = bf2f(u0.x) + bf2f(u1.x) + bf2f(u2.x);
        hv.y = bf2f(u0.y) + bf2f(u1.y) + bf2f(u2.y);
        hv.z = bf2f(u0.z) + bf2f(u1.z) + bf2f(u2.z);
        hv.w = bf2f(u0.w) + bf2f(u1.w) + bf2f(u2.w);
        reinterpret_cast<float4*>(&neigh[wave][(nl * 3 + nb) * 64])[k4] = hv;
    }
    #pragma unroll
    for (int it = 0; it < 2; it++) {
        int q = lane + it * 64;
        int nl = q >> 4, k4 = q & 15;
        const unsigned short* rp = Hs + (long)(base + nl) * 192;
        ushort4 u0 = reinterpret_cast<const ushort4*>(rp)[k4];
        ushort4 u1 = reinterpret_cast<const ushort4*>(rp + 64)[k4];
        ushort4 u2 = reinterpret_cast<const ushort4*>(rp + 128)[k4];
        float4 hv;
        hv.x = bf2f(u0.x) + bf2f(u1.x) + bf2f(u2.x);
        hv.y = bf2f(u0.y) + bf2f(u1.y) + bf2f(u2.y);
        hv.z = bf2f(u0.z) + bf2f(u1.z) + bf2f(u2.z);
        hv.w = bf2f(u0.w) + bf2f(u1.w) + bf2f(u2.w);
        reinterpret_cast<float4*>(&hc[wave][nl][0])[k4] = hv;
    }
    __syncthreads();

    {
        float am[8][3];
        float bmf = bm[lane];
        #pragma unroll
        for (int nl = 0; nl < 8; nl++)
            #pragma unroll
            for (int e = 0; e < 3; e++) am[nl][e] = bmf;
        for (int k = 0; k < 64; k++) {
            float w = Wm[k * 64 + lane];
            #pragma unroll
            for (int nl = 0; nl < 8; nl++)
                #pragma unroll
                for (int e = 0; e < 3; e++)
                    am[nl][e] += neigh[wave][(nl * 3 + e) * 64 + k] * w;
        }
        #pragma unroll
        for (int nl = 0; nl < 8; nl++) {
            float m = (fmaxf(am[nl][0], 0.f) + fmaxf(am[nl][1], 0.f) + fmaxf(am[nl][2], 0.f)) * (1.f / 3.f);
            hc[wave][nl][64 + lane] = m;
        }
    }
    __syncthreads();

    {
        float a0[8], a1[8];
        float b0 = bu1[lane], b1v = bu1[64 + lane];
        #pragma unroll
        for (int nl = 0; nl < 8; nl++) { a0[nl] = b0; a1[nl] = b1v; }
        for (int k = 0; k < 128; k++) {
            float w0 = Wu1[k * 128 + lane];
            float w1 = Wu1[k * 128 + 64 + lane];
            #pragma unroll
            for (int nl = 0; nl < 8; nl++) {
                float v = hc[wave][nl][k];
                a0[nl] += v * w0; a1[nl] += v * w1;
            }
        }
        #pragma unroll
        for (int nl = 0; nl < 8; nl++) {
            ub[wave][nl][lane]      = fmaxf(a0[nl], 0.f);
            ub[wave][nl][64 + lane] = fmaxf(a1[nl], 0.f);
        }
    }
    __syncthreads();

    float u20[8], u21[8];
    {
        float b0 = bu2[lane], b1v = bu2[64 + lane];
        #pragma unroll
        for (int nl = 0; nl < 8; nl++) { u20[nl] = b0; u21[nl] = b1v; }
        for (int k = 0; k < 128; k++) {
            float w0 = Wu2[k * 128 + lane];
            float w1 = Wu2[k * 128 + 64 + lane];
            #pragma unroll
            for (int nl = 0; nl < 8; nl++) {
                float v = ub[wave][nl][k];
                u20[nl] += v * w0; u21[nl] += v * w1;
            }
        }
        #pragma unroll
        for (int nl = 0; nl < 8; nl++) { u20[nl] = fmaxf(u20[nl], 0.f); u21[nl] = fmaxf(u21[nl], 0.f); }
    }

    float wm0a = Wmean[lane * 2 + 0], wm0b = Wmean[(64 + lane) * 2 + 0];
    float wm1a = Wmean[lane * 2 + 1], wm1b = Wmean[(64 + lane) * 2 + 1];
    float wva  = Wv[lane],            wvb  = Wv[64 + lane];
    #pragma unroll
    for (int nl = 0; nl < 8; nl++) {
        float p0 = u20[nl] * wm0a + u21[nl] * wm0b;
        float p1 = u20[nl] * wm1a + u21[nl] * wm1b;
        float p2 = u20[nl] * wva  + u21[nl] * wvb;
        #pragma unroll
        for (int m = 1; m < 64; m <<= 1) {
            p0 += __shfl_xor(p0, m, 64);
            p1 += __shfl_xor(p1, m, 64);
            p2 += __shfl_xor(p2, m, 64);
        }
        if (lane == 0) {
            int node = base + nl;
            out_mean[node * 2 + 0] = p0 + bmean[0];
            out_mean[node * 2 + 1] = p1 + bmean[1];
            out_val[node] = p2 + bv[0];
        }
    }
    if (blockIdx.x == 0 && tid < 2) out_std[tid] = expf(log_std[tid]);
}

extern "C" void kernel_launch(void* const* d_in, const int* in_sizes, int n_in,
                              void* d_out, int out_size, void* d_ws, size_t ws_size,
                              hipStream_t stream) {
    const float* x     = (const float*)d_in[0];
    const float* W1    = (const float*)d_in[1];
    const float* b1    = (const float*)d_in[2];
    const float* W2    = (const float*)d_in[3];
    const float* b2    = (const float*)d_in[4];
    const float* Wm    = (const float*)d_in[5];
    const float* bm    = (const float*)d_in[6];
    const float* Wu1   = (const float*)d_in[7];
    const float* bu1   = (const float*)d_in[8];
    const float* Wu2   = (const float*)d_in[9];
    const float* bu2   = (const float*)d_in[10];
    const float* Wmean = (const float*)d_in[11];
    const float* bmean = (const float*)d_in[12];
    const float* Wv    = (const float*)d_in[13];
    const float* bv    = (const float*)d_in[14];
    const float* lstd  = (const float*)d_in[15];

    float* out = (float*)d_out;
    float* out_mean = out;
    float* out_std  = out + 32768;
    float* out_val  = out + 32770;

    unsigned short* Hs = (unsigned short*)d_ws;
    float* sqv  = (float*)(Hs + (long)16384 * 192);
    int*   knn  = (int*)(sqv + 16384);
    float* pval = (float*)(knn + 16384 * 3);
    int*   pidx = (int*)(pval + (long)16384 * 16);

    k_embed<<<1024, 256, 0, stream>>>(x, W1, b1, W2, b2, Hs, sqv);
    k_knn<<<1024, 256, 0, stream>>>(Hs, sqv, pval, pidx);
    k_knn_merge<<<64, 256, 0, stream>>>(pval, pidx, knn);
    k_head<<<512, 256, 0, stream>>>(Hs, knn, Wm, bm, Wu1, bu1, Wu2, bu2,
                                    Wmean, bmean, Wv, bv, lstd,
                                    out_mean, out_std, out_val);
}